// Round 18
// baseline (750.890 us; speedup 1.0000x reference)
//
#include <hip/hip_runtime.h>
#include <hip/hip_bf16.h>

#define BATCH 2
#define SEQ   2048
#define DMODEL 2048
#define DINNER 4096
#define DXB   1024
#define NHEADS 64
#define NKV   16
#define HEADDIM 64
#define DSTATE 64
#define INTER 8192
#define DINPROJ 10304   // 4096 z + 1024 x + 1024 B + 4096 C + 64 dt
#define ROWS  (BATCH*SEQ)   // 4096
#define NC    32            // chunks per sequence
#define EPSV  1e-5f
#define TSTR  72            // padded LDS row stride for scan kernels

typedef short short8 __attribute__((ext_vector_type(8)));
typedef float f32x4 __attribute__((ext_vector_type(4)));

typedef const __attribute__((address_space(1))) unsigned int cg_u32;
typedef __attribute__((address_space(3))) unsigned int ls_u32;

static __device__ __forceinline__ void gll16(const void* g, void* l) {
    __builtin_amdgcn_global_load_lds((cg_u32*)g, (ls_u32*)l, 16, 0, 0);
}

static __device__ __forceinline__ unsigned short f2bf(float f) {
    unsigned int u = __float_as_uint(f);
    unsigned int r = (u + 0x7fffu + ((u >> 16) & 1u)) >> 16;
    return (unsigned short)r;
}
static __device__ __forceinline__ float bf2f(unsigned short h) {
    return __uint_as_float(((unsigned int)h) << 16);
}

// ---------------- prep: LayerNorm (blocks 0..ROWS-1) + all weight f32->bf16
// conversions (blocks ROWS..ROWS+2047) in ONE dispatch. LN is latency/compute
// bound, conversion is HBM-bound -> they overlap on the chip. ----------------
__global__ __launch_bounds__(256) void prep_kernel(const float* __restrict__ x,
                                                   const float* __restrict__ w,
                                                   const float* __restrict__ b,
                                                   unsigned short* __restrict__ hout,
                                                   const float* __restrict__ c0, unsigned short* __restrict__ d0, int n0,
                                                   const float* __restrict__ c1, unsigned short* __restrict__ d1, int n1,
                                                   const float* __restrict__ c2, unsigned short* __restrict__ d2, int n2,
                                                   const float* __restrict__ c3, unsigned short* __restrict__ d3, int n3) {
    int t = threadIdx.x;
    if (blockIdx.x >= ROWS) {
        int gtid = (blockIdx.x - ROWS) * 256 + t;
        int gstr = 2048 * 256;
        #define CSEG(S, D, N)                                     \
        for (int i = gtid; i < (N); i += gstr) {                  \
            float4 v = ((const float4*)(S))[i];                   \
            ushort4 o;                                            \
            o.x = f2bf(v.x); o.y = f2bf(v.y);                     \
            o.z = f2bf(v.z); o.w = f2bf(v.w);                     \
            ((ushort4*)(D))[i] = o;                               \
        }
        CSEG(c0, d0, n0)
        CSEG(c1, d1, n1)
        CSEG(c2, d2, n2)
        CSEG(c3, d3, n3)
        #undef CSEG
        return;
    }
    int row = blockIdx.x;
    const float* xr = x + (size_t)row * DMODEL;
    float v[8];
    float4 v0 = *(const float4*)&xr[t * 8];
    float4 v1 = *(const float4*)&xr[t * 8 + 4];
    v[0]=v0.x; v[1]=v0.y; v[2]=v0.z; v[3]=v0.w; v[4]=v1.x; v[5]=v1.y; v[6]=v1.z; v[7]=v1.w;
    float sm = 0.f, sq = 0.f;
    #pragma unroll
    for (int i = 0; i < 8; ++i) { sm += v[i]; sq += v[i]*v[i]; }
    #pragma unroll
    for (int off = 1; off < 64; off <<= 1) { sm += __shfl_xor(sm, off); sq += __shfl_xor(sq, off); }
    __shared__ float sa[4], sb[4];
    int lane = t & 63, wv = t >> 6;
    if (lane == 0) { sa[wv] = sm; sb[wv] = sq; }
    __syncthreads();
    sm = sa[0]+sa[1]+sa[2]+sa[3];
    sq = sb[0]+sb[1]+sb[2]+sb[3];
    float mu = sm / DMODEL;
    float var = sq / DMODEL - mu * mu;
    float sc = rsqrtf(var + EPSV);
    unsigned short* ho = hout + (size_t)row * DMODEL + t * 8;
    #pragma unroll
    for (int i = 0; i < 8; ++i) {
        int d = t * 8 + i;
        ho[i] = f2bf((v[i] - mu) * sc * w[d] + b[d]);
    }
}

// ========== gemm_q: 256x256 tile, BK=32, ring-4 LDS (128KB), loose rhythm =========
// 8 waves (2M x 4N), wave tile 128x64 (8x4 frags of 16x16x32). Counted vmcnt(8)
// (3-tile issue-to-use distance), 1 barrier/K-tile, setprio, by-fast XCD swizzle.
// Swizzle (both-sides involution, 64B rows of 4x16B chunks): chunk ^= (row>>1)&3.
// EPI 1: gelu->bf16. EPI 3: bf16.
#define QSLOT 32768
template <int EPI>
__global__ __launch_bounds__(512, 1) void gemm_q(
    const unsigned short* __restrict__ A, const unsigned short* __restrict__ B,
    int M, int N, int K, int nby,
    float* __restrict__ outF, unsigned short* __restrict__ outH,
    const float* __restrict__ bias) {
    __shared__ __align__(16) char smem[4 * QSLOT];
    int t = threadIdx.x, lane = t & 63, w = t >> 6;
    int nwg = gridDim.x, cpx = nwg >> 3;
    int logical = (blockIdx.x & 7) * cpx + (blockIdx.x >> 3);
    int by = logical % nby, bx = logical / nby;   // by-fast: B-tile reuse in L2
    int brow = by * 256, bcol = bx * 256;
    int wm = w >> 2, wn = w & 3;
    int wrb = wm * 128, wcb = wn * 64;

    int lrow4 = lane >> 2;
    int scs = ((lane & 3) ^ ((lane >> 3) & 3)) << 3;   // element offset in 32-elem row
    const unsigned short* pa[2];
    #pragma unroll
    for (int j = 0; j < 2; ++j)
        pa[j] = A + (size_t)(brow + w * 32 + j * 16 + lrow4) * K + scs;
    const unsigned short* pb[2];
    #pragma unroll
    for (int j = 0; j < 2; ++j) {
        int r = bcol + w * 32 + j * 16 + lrow4;
        if (r > N - 1) r = N - 1;
        pb[j] = B + (size_t)r * K + scs;
    }
    auto stage = [&](int kt) {
        int slot = kt & 3;
        #pragma unroll
        for (int j = 0; j < 2; ++j) {
            gll16(pa[j], smem + slot * QSLOT + (w * 32 + j * 16) * 64);
            pa[j] += 32;
        }
        #pragma unroll
        for (int j = 0; j < 2; ++j) {
            gll16(pb[j], smem + slot * QSLOT + 16384 + (w * 32 + j * 16) * 64);
            pb[j] += 32;
        }
    };

    int arow = lane & 15;
    int rsw = ((lane >> 4) ^ ((arow >> 1) & 3)) << 4;  // byte offset of chunk in row

    f32x4 acc[8][4] = {};
    const int NT = K >> 5;
    stage(0); stage(1); stage(2);

    for (int kt = 0; kt < NT; ++kt) {
        if (kt + 2 < NT)      { asm volatile("s_waitcnt vmcnt(8)" ::: "memory"); }
        else if (kt + 1 < NT) { asm volatile("s_waitcnt vmcnt(4)" ::: "memory"); }
        else                  { asm volatile("s_waitcnt vmcnt(0)" ::: "memory"); }
        __builtin_amdgcn_s_barrier();
        asm volatile("" ::: "memory");
        const char* Ab = smem + (kt & 3) * QSLOT;
        const char* Bb = Ab + 16384;
        short8 af[8], bfv[4];
        #pragma unroll
        for (int f = 0; f < 8; ++f) {
            int r = wrb + f * 16 + arow;
            af[f] = *(const short8*)(Ab + r * 64 + rsw);
        }
        #pragma unroll
        for (int n = 0; n < 4; ++n) {
            int r = wcb + n * 16 + arow;
            bfv[n] = *(const short8*)(Bb + r * 64 + rsw);
        }
        if (kt + 3 < NT) stage(kt + 3);
        __builtin_amdgcn_s_setprio(1);
        #pragma unroll
        for (int f = 0; f < 8; ++f)
            #pragma unroll
            for (int n = 0; n < 4; ++n)
                acc[f][n] = __builtin_amdgcn_mfma_f32_16x16x32_bf16(af[f], bfv[n], acc[f][n], 0, 0, 0);
        __builtin_amdgcn_s_setprio(0);
    }

    int rlane = (lane >> 4) << 2, clane = lane & 15;
    #pragma unroll
    for (int f = 0; f < 8; ++f) {
        #pragma unroll
        for (int n = 0; n < 4; ++n) {
            int col = bcol + wcb + n * 16 + clane;
            if (col < N) {
                #pragma unroll
                for (int j = 0; j < 4; ++j) {
                    int row = brow + wrb + f * 16 + rlane + j;
                    size_t idx = (size_t)row * N + col;
                    float v = acc[f][n][j];
                    if constexpr (EPI == 1) {
                        v += bias[col];
                        float g = 0.5f * v * (1.f + tanhf(0.7978845608f * (v + 0.044715f * v * v * v)));
                        outH[idx] = f2bf(g);
                    } else {
                        outH[idx] = f2bf(v);
                    }
                }
            }
        }
    }
}

// ---------------- gemm_p: 128x256 R5 skeleton, BK=64, ring-3 (combined GEMM) ------
// Dual-source K: segment 1 = (A,B) stride K1, segment 2 = (A2,B2) stride K-K1.
// EPI 4: acc+bias+add2 -> f32.
#define SLOTSZ 49152
template <int EPI>
__global__ __launch_bounds__(512, 2) void gemm_p(
    const unsigned short* __restrict__ A, const unsigned short* __restrict__ B,
    int M, int N, int K, int nby,
    float* __restrict__ outF, unsigned short* __restrict__ outH,
    const float* __restrict__ bias, const float* __restrict__ add1,
    const float* __restrict__ add2,
    const unsigned short* __restrict__ A2, const unsigned short* __restrict__ B2,
    int K1) {
    __shared__ __align__(16) char smem[3 * SLOTSZ];
    int t = threadIdx.x, lane = t & 63, w = t >> 6;
    int nwg = gridDim.x, cpx = nwg >> 3;
    int logical = (blockIdx.x & 7) * cpx + (blockIdx.x >> 3);
    int by = logical % nby, bx = logical / nby;
    int brow = by * 128, bcol = bx * 256;
    int wr = w >> 2, wc = w & 3;
    int wrb = wr * 64, wcb = wc * 64;

    int lr8 = lane >> 3;
    int lch = ((lane & 7) ^ lr8) << 3;
    const unsigned short* pa[2];
    #pragma unroll
    for (int j = 0; j < 2; ++j)
        pa[j] = A + (size_t)(brow + w * 16 + j * 8 + lr8) * K1 + lch;
    const unsigned short* pb[4];
    #pragma unroll
    for (int j = 0; j < 4; ++j) {
        int r = bcol + w * 32 + j * 8 + lr8;
        if (r > N - 1) r = N - 1;
        pb[j] = B + (size_t)r * K1 + lch;
    }
    auto stageA = [&](int slot, int j) {
        gll16(pa[j], smem + slot * SLOTSZ + (w * 16 + j * 8) * 128);
        pa[j] += 64;
    };
    auto stageB = [&](int slot, int j) {
        gll16(pb[j], smem + slot * SLOTSZ + 16384 + (w * 32 + j * 8) * 128);
        pb[j] += 64;
    };

    int arow = lane & 15;
    int swz0 = (((lane >> 4) ^ (lane & 7)) << 4);

    f32x4 acc[4][4] = {};
    const int NT = K >> 6;
    const int KS = K1 >> 6;
    #pragma unroll
    for (int j = 0; j < 2; ++j) stageA(0, j);
    #pragma unroll
    for (int j = 0; j < 4; ++j) stageB(0, j);
    #pragma unroll
    for (int j = 0; j < 2; ++j) stageA(1, j);
    #pragma unroll
    for (int j = 0; j < 4; ++j) stageB(1, j);

    int slot = 0, slot2 = 2;
    for (int kt = 0; kt < NT; ++kt) {
        if (kt + 1 < NT) { asm volatile("s_waitcnt vmcnt(6)" ::: "memory"); }
        else             { asm volatile("s_waitcnt vmcnt(0)" ::: "memory"); }
        __builtin_amdgcn_s_barrier();
        asm volatile("" ::: "memory");
        const char* Ab = smem + slot * SLOTSZ;
        const char* Bb = Ab + 16384;
        bool st = (kt + 2 < NT);
        if (B2 != nullptr && kt + 2 == KS) {
            int ld2 = K - K1;
            #pragma unroll
            for (int j = 0; j < 2; ++j)
                pa[j] = A2 + (size_t)(brow + w * 16 + j * 8 + lr8) * ld2 + lch;
            #pragma unroll
            for (int j = 0; j < 4; ++j) {
                int r = bcol + w * 32 + j * 8 + lr8;
                if (r > N - 1) r = N - 1;
                pb[j] = B2 + (size_t)r * ld2 + lch;
            }
        }
        short8 af[4], bfv[4];
        #pragma unroll
        for (int f = 0; f < 4; ++f)
            af[f] = *(const short8*)(Ab + (wrb + f * 16 + arow) * 128 + swz0);
        #pragma unroll
        for (int n = 0; n < 4; ++n)
            bfv[n] = *(const short8*)(Bb + (wcb + n * 16 + arow) * 128 + swz0);
        if (st) { stageA(slot2, 0); stageA(slot2, 1); stageB(slot2, 0); }
        __builtin_amdgcn_s_setprio(1);
        #pragma unroll
        for (int f = 0; f < 4; ++f)
            #pragma unroll
            for (int n = 0; n < 4; ++n)
                acc[f][n] = __builtin_amdgcn_mfma_f32_16x16x32_bf16(af[f], bfv[n], acc[f][n], 0, 0, 0);
        __builtin_amdgcn_s_setprio(0);
        #pragma unroll
        for (int f = 0; f < 4; ++f)
            af[f] = *(const short8*)(Ab + (wrb + f * 16 + arow) * 128 + (swz0 ^ 64));
        #pragma unroll
        for (int n = 0; n < 4; ++n)
            bfv[n] = *(const short8*)(Bb + (wcb + n * 16 + arow) * 128 + (swz0 ^ 64));
        if (st) { stageB(slot2, 1); stageB(slot2, 2); stageB(slot2, 3); }
        __builtin_amdgcn_s_setprio(1);
        #pragma unroll
        for (int f = 0; f < 4; ++f)
            #pragma unroll
            for (int n = 0; n < 4; ++n)
                acc[f][n] = __builtin_amdgcn_mfma_f32_16x16x32_bf16(af[f], bfv[n], acc[f][n], 0, 0, 0);
        __builtin_amdgcn_s_setprio(0);
        slot  = (slot  == 2) ? 0 : slot + 1;
        slot2 = (slot2 == 2) ? 0 : slot2 + 1;
    }

    int rlane = (lane >> 4) << 2, clane = lane & 15;
    #pragma unroll
    for (int f = 0; f < 4; ++f) {
        #pragma unroll
        for (int n = 0; n < 4; ++n) {
            int col = bcol + wcb + n * 16 + clane;
            if (col < N) {
                #pragma unroll
                for (int j = 0; j < 4; ++j) {
                    int row = brow + wrb + f * 16 + rlane + j;
                    size_t idx = (size_t)row * N + col;
                    float v = acc[f][n][j];
                    if constexpr (EPI == 4) {
                        outF[idx] = v + bias[col] + add2[idx];
                    } else {
                        outF[idx] = v;
                    }
                }
            }
        }
    }
}

// 64x64x64 bf16 MFMA on TSTR-padded LDS tiles.
static __device__ __forceinline__ void mm64(const unsigned short* Al, const unsigned short* Bl,
                                            f32x4* acc, int w, int lane) {
    int lr = lane & 15, kg = (lane >> 4) << 3;
    #pragma unroll
    for (int ks = 0; ks < 2; ++ks) {
        short8 a = *(const short8*)&Al[(w * 16 + lr) * TSTR + ks * 32 + kg];
        #pragma unroll
        for (int fn = 0; fn < 4; ++fn) {
            short8 bb = *(const short8*)&Bl[(fn * 16 + lr) * TSTR + ks * 32 + kg];
            acc[fn] = __builtin_amdgcn_mfma_f32_16x16x32_bf16(a, bb, acc[fn], 0, 0, 0);
        }
    }
}

// ---------------- K1: per-(b,h,chunk) intra-chunk work (dt fused) ----------------
__global__ __launch_bounds__(256) void chunk_front(const unsigned short* __restrict__ zx,
                                                   const float* __restrict__ dt_bias,
                                                   const float* __restrict__ A_log,
                                                   float* __restrict__ pcum,
                                                   unsigned short* __restrict__ ybuf,
                                                   unsigned short* __restrict__ Sbuf) {
    __shared__ __align__(16) unsigned short Cs[64*TSTR], Bsr[64*TSTR], Btr[64*TSTR],
                                            Xtr[64*TSTR], Xw[64*TSTR], Wsm[64*TSTR];
    __shared__ float dts[64], clg[64];
    int t = threadIdx.x, lane = t & 63, w = t >> 6;
    int bid = blockIdx.x;
    int c = bid & 31, h = (bid >> 5) & 63, b = bid >> 11, g = h >> 2;
    int row0 = (b << 11) + (c << 6);

    if (t < 64) {
        float raw = bf2f(zx[(size_t)(row0 + t) * DINPROJ + 10240 + h]) + dt_bias[h];
        float dt = raw > 20.f ? raw : log1pf(expf(raw));
        dts[t] = dt;
        float v = dt * (-expf(A_log[h]));
        #pragma unroll
        for (int off = 1; off < 64; off <<= 1) {
            float o = __shfl_up(v, off);
            if (lane >= off) v += o;
        }
        clg[t] = v;
        pcum[(size_t)(row0 + t) * 64 + h] = expf(v);
    }
    ushort4 xr[4];
    #pragma unroll
    for (int i = 0; i < 4; ++i) {
        int q = i * 256 + t, s = q >> 4, d4 = (q & 15) << 2;
        const unsigned short* rp = zx + (size_t)(row0 + s) * DINPROJ;
        ushort4 cv = *(const ushort4*)&rp[6144 + h * 64 + d4];
        *(ushort4*)&Cs[s * TSTR + d4] = cv;
        ushort4 bv = *(const ushort4*)&rp[5120 + g * 64 + d4];
        *(ushort4*)&Bsr[s * TSTR + d4] = bv;
        Btr[(d4 + 0) * TSTR + s] = bv.x; Btr[(d4 + 1) * TSTR + s] = bv.y;
        Btr[(d4 + 2) * TSTR + s] = bv.z; Btr[(d4 + 3) * TSTR + s] = bv.w;
        ushort4 xv = *(const ushort4*)&rp[4096 + g * 64 + d4];
        Xtr[(d4 + 0) * TSTR + s] = xv.x; Xtr[(d4 + 1) * TSTR + s] = xv.y;
        Xtr[(d4 + 2) * TSTR + s] = xv.z; Xtr[(d4 + 3) * TSTR + s] = xv.w;
        xr[i] = xv;
    }
    __syncthreads();
    float cl63 = clg[63];
    #pragma unroll
    for (int i = 0; i < 4; ++i) {
        int q = i * 256 + t, s = q >> 4, d4 = (q & 15) << 2;
        float ws = dts[s] * expf(cl63 - clg[s]);
        Xw[(d4 + 0) * TSTR + s] = f2bf(bf2f(xr[i].x) * ws);
        Xw[(d4 + 1) * TSTR + s] = f2bf(bf2f(xr[i].y) * ws);
        Xw[(d4 + 2) * TSTR + s] = f2bf(bf2f(xr[i].z) * ws);
        Xw[(d4 + 3) * TSTR + s] = f2bf(bf2f(xr[i].w) * ws);
    }
    __syncthreads();
    f32x4 accG[4] = {};
    mm64(Cs, Bsr, accG, w, lane);
    int rl = (lane >> 4) << 2, cl = lane & 15;
    #pragma unroll
    for (int fn = 0; fn < 4; ++fn) {
        #pragma unroll
        for (int j = 0; j < 4; ++j) {
            int tr = w * 16 + rl + j, rc = fn * 16 + cl;
            float val = 0.f;
            if (rc <= tr) val = accG[fn][j] * expf(clg[tr] - clg[rc]) * dts[rc];
            Wsm[tr * TSTR + rc] = f2bf(val);
        }
    }
    __syncthreads();
    f32x4 accY[4] = {};
    mm64(Wsm, Xtr, accY, w, lane);
    f32x4 accS[4] = {};
    mm64(Xw, Btr, accS, w, lane);
    size_t cb = (size_t)((((b << 6) + h) << 5) + c) * 4096;
    #pragma unroll
    for (int fn = 0; fn < 4; ++fn) {
        #pragma unroll
        for (int j = 0; j < 4; ++j) {
            int tr = w * 16 + rl + j, pc = fn * 16 + cl;
            ybuf[(size_t)(row0 + tr) * DINNER + h * 64 + pc] = f2bf(accY[fn][j]);
            Sbuf[cb + tr * 64 + pc] = f2bf(accS[fn][j]);
        }
    }
}

// ---------------- K2: inter-chunk state recurrence (in-place S -> H0) ----------------
__global__ __launch_bounds__(256) void chunk_state(unsigned short* __restrict__ SH,
                                                   const float* __restrict__ pcum) {
    int bid = blockIdx.x;
    int q = bid & 3, bh = bid >> 2;
    int b = bh >> 6, h = bh & 63;
    int t = threadIdx.x;
    float H[4];
    #pragma unroll
    for (int j = 0; j < 4; ++j) H[j] = 0.f;
    for (int c = 0; c < NC; ++c) {
        size_t base = (size_t)((((b << 6) + h) << 5) + c) * 4096 + q * 1024;
        float Tc = pcum[(size_t)((b << 11) + (c << 6) + 63) * 64 + h];
        #pragma unroll
        for (int j = 0; j < 4; ++j) {
            int e = j * 256 + t;
            unsigned short sv = SH[base + e];
            SH[base + e] = f2bf(H[j]);
            H[j] = H[j] * Tc + bf2f(sv);
        }
    }
}

// ---------------- K3: y += p_t * (C_t . H0) + Dp * x ----------------
__global__ __launch_bounds__(256) void chunk_back(const unsigned short* __restrict__ zx,
                                                  const unsigned short* __restrict__ SH,
                                                  const float* __restrict__ pcum,
                                                  const float* __restrict__ Dp,
                                                  unsigned short* __restrict__ ybuf) {
    __shared__ __align__(16) unsigned short Cs[64*TSTR], Hs[64*TSTR];
    __shared__ float ps[64];
    int t = threadIdx.x, lane = t & 63, w = t >> 6;
    int bid = blockIdx.x;
    int c = bid & 31, h = (bid >> 5) & 63, b = bid >> 11, g = h >> 2;
    int row0 = (b << 11) + (c << 6);
    size_t cb = (size_t)((((b << 6) + h) << 5) + c) * 4096;
    #pragma unroll
    for (int i = 0; i < 4; ++i) {
        int q = i * 256 + t, s = q >> 4, d4 = (q & 15) << 2;
        *(ushort4*)&Cs[s * TSTR + d4] =
            *(const ushort4*)&zx[(size_t)(row0 + s) * DINPROJ + 6144 + h * 64 + d4];
        *(ushort4*)&Hs[s * TSTR + d4] = *(const ushort4*)&SH[cb + s * 64 + d4];
    }
    if (t < 64) ps[t] = pcum[(size_t)(row0 + t) * 64 + h];
    __syncthreads();
    f32x4 acc[4] = {};
    mm64(Cs, Hs, acc, w, lane);
    float Dph = Dp[h];
    int rl = (lane >> 4) << 2, cl = lane & 15;
    #pragma unroll
    for (int fn = 0; fn < 4; ++fn) {
        #pragma unroll
        for (int j = 0; j < 4; ++j) {
            int tr = w * 16 + rl + j, pc = fn * 16 + cl;
            size_t yi = (size_t)(row0 + tr) * DINNER + h * 64 + pc;
            float xv = bf2f(zx[(size_t)(row0 + tr) * DINPROJ + 4096 + g * 64 + pc]);
            ybuf[yi] = f2bf(bf2f(ybuf[yi]) + acc[fn][j] * ps[tr] + Dph * xv);
        }
    }
}

// ---------------- gate (silu) + RMSNorm -> bf16 yf ----------------
__global__ __launch_bounds__(256) void gate_kernel(const unsigned short* __restrict__ y,
                                                   const unsigned short* __restrict__ zx,
                                                   const float* __restrict__ norm_w,
                                                   unsigned short* __restrict__ yf) {
    int row = blockIdx.x;
    int t = threadIdx.x;
    float v[16];
    float s2 = 0.f;
    #pragma unroll
    for (int i = 0; i < 16; ++i) {
        int d = i * 256 + t;
        float yv = bf2f(y[(size_t)row * DINNER + d]);
        float zv = bf2f(zx[(size_t)row * DINPROJ + d]);
        float gt = zv / (1.f + expf(-zv));
        v[i] = yv * gt;
        s2 += v[i] * v[i];
    }
    #pragma unroll
    for (int off = 1; off < 64; off <<= 1) s2 += __shfl_xor(s2, off);
    __shared__ float sb[4];
    int lane = t & 63, wv = t >> 6;
    if (lane == 0) sb[wv] = s2;
    __syncthreads();
    s2 = sb[0] + sb[1] + sb[2] + sb[3];
    float sc = rsqrtf(s2 / DINNER + EPSV);
    #pragma unroll
    for (int i = 0; i < 16; ++i) {
        int d = i * 256 + t;
        yf[(size_t)row * DINNER + d] = f2bf(v[i] * sc * norm_w[d]);
    }
}

extern "C" void kernel_launch(void* const* d_in, const int* in_sizes, int n_in,
                              void* d_out, int out_size, void* d_ws, size_t ws_size,
                              hipStream_t stream) {
    const float* hid   = (const float*)d_in[0];
    const float* ln_w  = (const float*)d_in[1];
    const float* ln_b  = (const float*)d_in[2];
    const float* w_inp = (const float*)d_in[3];
    const float* dtb   = (const float*)d_in[4];
    const float* A_log = (const float*)d_in[5];
    const float* Dp    = (const float*)d_in[6];
    const float* nw    = (const float*)d_in[7];
    const float* w_out = (const float*)d_in[8];
    const float* w_fc1 = (const float*)d_in[9];
    const float* fc1_b = (const float*)d_in[10];
    const float* w_fc2 = (const float*)d_in[11];
    const float* fc2_b = (const float*)d_in[12];

    char* ws = (char*)d_ws;
    size_t off = 0;
    auto alloc = [&](size_t bytes) { size_t o = off; off += (bytes + 255) & ~(size_t)255; return o; };
    size_t o_h    = alloc((size_t)ROWS * DMODEL * 2);
    size_t o_wi   = alloc((size_t)DINPROJ * DMODEL * 2);
    size_t o_wo   = alloc((size_t)DMODEL * DINNER * 2);
    size_t o_wf1  = alloc((size_t)INTER * DMODEL * 2);
    size_t o_wf2  = alloc((size_t)DMODEL * INTER * 2);
    size_t o_zx   = alloc((size_t)ROWS * DINPROJ * 2);
    size_t o_pc   = alloc((size_t)ROWS * NHEADS * 4);
    size_t o_y    = alloc((size_t)ROWS * DINNER * 2);
    size_t o_yf   = alloc((size_t)ROWS * DINNER * 2);
    size_t o_S    = alloc((size_t)BATCH * NHEADS * NC * HEADDIM * DSTATE * 2);

    unsigned short* h_bf  = (unsigned short*)(ws + o_h);
    unsigned short* wbi   = (unsigned short*)(ws + o_wi);
    unsigned short* wbo   = (unsigned short*)(ws + o_wo);
    unsigned short* wbf1  = (unsigned short*)(ws + o_wf1);
    unsigned short* wbf2  = (unsigned short*)(ws + o_wf2);
    unsigned short* zx    = (unsigned short*)(ws + o_zx);
    float* pcum           = (float*)(ws + o_pc);
    unsigned short* ybuf  = (unsigned short*)(ws + o_y);
    unsigned short* yf    = (unsigned short*)(ws + o_yf);
    unsigned short* Sbuf  = (unsigned short*)(ws + o_S);
    unsigned short* gelu  = (unsigned short*)(ws + o_zx);    // alias: zx dead after gate
    float* outF           = (float*)d_out;

    // 0) LayerNorm + all weight conversions in ONE dispatch (independent work,
    //    LN is compute/latency-bound, conversion is HBM-bound -> overlap)
    prep_kernel<<<ROWS + 2048, 256, 0, stream>>>(
        hid, ln_w, ln_b, h_bf,
        w_inp, wbi,  (DINPROJ * DMODEL) / 4,
        w_out, wbo,  (DMODEL * DINNER) / 4,
        w_fc1, wbf1, (INTER * DMODEL) / 4,
        w_fc2, wbf2, (DMODEL * INTER) / 4);
    // 1) in_proj GEMM -> zx (bf16); 256^2 tiles: 41 col x 16 row = 656 blocks
    gemm_q<3><<<41 * 16, 512, 0, stream>>>(
        h_bf, wbi, ROWS, DINPROJ, DMODEL, 16, nullptr, zx, nullptr);
    // 2) chunked SSD scan
    chunk_front<<<BATCH * NHEADS * NC, 256, 0, stream>>>(zx, dtb, A_log, pcum, ybuf, Sbuf);
    chunk_state<<<BATCH * NHEADS * 4, 256, 0, stream>>>(Sbuf, pcum);
    chunk_back<<<BATCH * NHEADS * NC, 256, 0, stream>>>(zx, Sbuf, pcum, Dp, ybuf);
    // 3) gate + RMSNorm -> yf (bf16)
    gate_kernel<<<ROWS, 256, 0, stream>>>(ybuf, zx, nw, yf);
    // 4) fc1 GEMM + gelu -> gelu (bf16); 256^2 tiles: 32 col x 16 row = 512 blocks
    gemm_q<1><<<32 * 16, 512, 0, stream>>>(
        h_bf, wbf1, ROWS, INTER, DMODEL, 16, nullptr, gelu, fc1_b);
    // 5) combined (out_proj + fc2) GEMM over concatenated K = 4096 + 8192 (128x256)
    gemm_p<4><<<8 * 32, 512, 0, stream>>>(
        yf, wbo, ROWS, DMODEL, DINNER + INTER, 32, outF, nullptr, fc2_b, nullptr, hid,
        gelu, wbf2, DINNER);
}

// Round 20
// 748.846 us; speedup vs baseline: 1.0027x; 1.0027x over previous
//
#include <hip/hip_runtime.h>
#include <hip/hip_bf16.h>

#define BATCH 2
#define SEQ   2048
#define DMODEL 2048
#define DINNER 4096
#define DXB   1024
#define NHEADS 64
#define NKV   16
#define HEADDIM 64
#define DSTATE 64
#define INTER 8192
#define DINPROJ 10304   // 4096 z + 1024 x + 1024 B + 4096 C + 64 dt
#define ROWS  (BATCH*SEQ)   // 4096
#define NC    32            // chunks per sequence
#define EPSV  1e-5f
#define TSTR  72            // padded LDS row stride for scan kernels

typedef short short8 __attribute__((ext_vector_type(8)));
typedef float f32x4 __attribute__((ext_vector_type(4)));

typedef const __attribute__((address_space(1))) unsigned int cg_u32;
typedef __attribute__((address_space(3))) unsigned int ls_u32;

static __device__ __forceinline__ void gll16(const void* g, void* l) {
    __builtin_amdgcn_global_load_lds((cg_u32*)g, (ls_u32*)l, 16, 0, 0);
}

static __device__ __forceinline__ unsigned short f2bf(float f) {
    unsigned int u = __float_as_uint(f);
    unsigned int r = (u + 0x7fffu + ((u >> 16) & 1u)) >> 16;
    return (unsigned short)r;
}
static __device__ __forceinline__ float bf2f(unsigned short h) {
    return __uint_as_float(((unsigned int)h) << 16);
}

// ---------------- prep: LayerNorm + all weight f32->bf16 conversions ----------
__global__ __launch_bounds__(256) void prep_kernel(const float* __restrict__ x,
                                                   const float* __restrict__ w,
                                                   const float* __restrict__ b,
                                                   unsigned short* __restrict__ hout,
                                                   const float* __restrict__ c0, unsigned short* __restrict__ d0, int n0,
                                                   const float* __restrict__ c1, unsigned short* __restrict__ d1, int n1,
                                                   const float* __restrict__ c2, unsigned short* __restrict__ d2, int n2,
                                                   const float* __restrict__ c3, unsigned short* __restrict__ d3, int n3) {
    int t = threadIdx.x;
    if (blockIdx.x >= ROWS) {
        int gtid = (blockIdx.x - ROWS) * 256 + t;
        int gstr = 2048 * 256;
        #define CSEG(S, D, N)                                     \
        for (int i = gtid; i < (N); i += gstr) {                  \
            float4 v = ((const float4*)(S))[i];                   \
            ushort4 o;                                            \
            o.x = f2bf(v.x); o.y = f2bf(v.y);                     \
            o.z = f2bf(v.z); o.w = f2bf(v.w);                     \
            ((ushort4*)(D))[i] = o;                               \
        }
        CSEG(c0, d0, n0)
        CSEG(c1, d1, n1)
        CSEG(c2, d2, n2)
        CSEG(c3, d3, n3)
        #undef CSEG
        return;
    }
    int row = blockIdx.x;
    const float* xr = x + (size_t)row * DMODEL;
    float v[8];
    float4 v0 = *(const float4*)&xr[t * 8];
    float4 v1 = *(const float4*)&xr[t * 8 + 4];
    v[0]=v0.x; v[1]=v0.y; v[2]=v0.z; v[3]=v0.w; v[4]=v1.x; v[5]=v1.y; v[6]=v1.z; v[7]=v1.w;
    float sm = 0.f, sq = 0.f;
    #pragma unroll
    for (int i = 0; i < 8; ++i) { sm += v[i]; sq += v[i]*v[i]; }
    #pragma unroll
    for (int off = 1; off < 64; off <<= 1) { sm += __shfl_xor(sm, off); sq += __shfl_xor(sq, off); }
    __shared__ float sa[4], sb[4];
    int lane = t & 63, wv = t >> 6;
    if (lane == 0) { sa[wv] = sm; sb[wv] = sq; }
    __syncthreads();
    sm = sa[0]+sa[1]+sa[2]+sa[3];
    sq = sb[0]+sb[1]+sb[2]+sb[3];
    float mu = sm / DMODEL;
    float var = sq / DMODEL - mu * mu;
    float sc = rsqrtf(var + EPSV);
    unsigned short* ho = hout + (size_t)row * DMODEL + t * 8;
    #pragma unroll
    for (int i = 0; i < 8; ++i) {
        int d = t * 8 + i;
        ho[i] = f2bf((v[i] - mu) * sc * w[d] + b[d]);
    }
}

// ========== gemm_q: 256x256 tile, BK=32, ring-4 LDS (128KB), loose rhythm =========
// 8 waves (2M x 4N), wave tile 128x64 (8x4 frags of 16x16x32). Counted vmcnt(8)
// (3-tile issue-to-use distance), 1 barrier/K-tile, setprio, by-fast XCD swizzle.
// Swizzle (both-sides involution, 64B rows of 4x16B chunks): chunk ^= (row>>1)&3.
// EPI 1: gelu->bf16. EPI 3: bf16.
#define QSLOT 32768
template <int EPI>
__global__ __launch_bounds__(512, 1) void gemm_q(
    const unsigned short* __restrict__ A, const unsigned short* __restrict__ B,
    int M, int N, int K, int nby,
    float* __restrict__ outF, unsigned short* __restrict__ outH,
    const float* __restrict__ bias) {
    __shared__ __align__(16) char smem[4 * QSLOT];
    int t = threadIdx.x, lane = t & 63, w = t >> 6;
    int nwg = gridDim.x, cpx = nwg >> 3;
    int logical = (blockIdx.x & 7) * cpx + (blockIdx.x >> 3);
    int by = logical % nby, bx = logical / nby;   // by-fast: B-tile reuse in L2
    int brow = by * 256, bcol = bx * 256;
    int wm = w >> 2, wn = w & 3;
    int wrb = wm * 128, wcb = wn * 64;

    int lrow4 = lane >> 2;
    int scs = ((lane & 3) ^ ((lane >> 3) & 3)) << 3;   // element offset in 32-elem row
    const unsigned short* pa[2];
    #pragma unroll
    for (int j = 0; j < 2; ++j)
        pa[j] = A + (size_t)(brow + w * 32 + j * 16 + lrow4) * K + scs;
    const unsigned short* pb[2];
    #pragma unroll
    for (int j = 0; j < 2; ++j) {
        int r = bcol + w * 32 + j * 16 + lrow4;
        if (r > N - 1) r = N - 1;
        pb[j] = B + (size_t)r * K + scs;
    }
    auto stage = [&](int kt) {
        int slot = kt & 3;
        #pragma unroll
        for (int j = 0; j < 2; ++j) {
            gll16(pa[j], smem + slot * QSLOT + (w * 32 + j * 16) * 64);
            pa[j] += 32;
        }
        #pragma unroll
        for (int j = 0; j < 2; ++j) {
            gll16(pb[j], smem + slot * QSLOT + 16384 + (w * 32 + j * 16) * 64);
            pb[j] += 32;
        }
    };

    int arow = lane & 15;
    int rsw = ((lane >> 4) ^ ((arow >> 1) & 3)) << 4;  // byte offset of chunk in row

    f32x4 acc[8][4] = {};
    const int NT = K >> 5;
    stage(0); stage(1); stage(2);

    for (int kt = 0; kt < NT; ++kt) {
        if (kt + 2 < NT)      { asm volatile("s_waitcnt vmcnt(8)" ::: "memory"); }
        else if (kt + 1 < NT) { asm volatile("s_waitcnt vmcnt(4)" ::: "memory"); }
        else                  { asm volatile("s_waitcnt vmcnt(0)" ::: "memory"); }
        __builtin_amdgcn_s_barrier();
        asm volatile("" ::: "memory");
        const char* Ab = smem + (kt & 3) * QSLOT;
        const char* Bb = Ab + 16384;
        short8 af[8], bfv[4];
        #pragma unroll
        for (int f = 0; f < 8; ++f) {
            int r = wrb + f * 16 + arow;
            af[f] = *(const short8*)(Ab + r * 64 + rsw);
        }
        #pragma unroll
        for (int n = 0; n < 4; ++n) {
            int r = wcb + n * 16 + arow;
            bfv[n] = *(const short8*)(Bb + r * 64 + rsw);
        }
        if (kt + 3 < NT) stage(kt + 3);
        __builtin_amdgcn_s_setprio(1);
        #pragma unroll
        for (int f = 0; f < 8; ++f)
            #pragma unroll
            for (int n = 0; n < 4; ++n)
                acc[f][n] = __builtin_amdgcn_mfma_f32_16x16x32_bf16(af[f], bfv[n], acc[f][n], 0, 0, 0);
        __builtin_amdgcn_s_setprio(0);
    }

    int rlane = (lane >> 4) << 2, clane = lane & 15;
    #pragma unroll
    for (int f = 0; f < 8; ++f) {
        #pragma unroll
        for (int n = 0; n < 4; ++n) {
            int col = bcol + wcb + n * 16 + clane;
            if (col < N) {
                #pragma unroll
                for (int j = 0; j < 4; ++j) {
                    int row = brow + wrb + f * 16 + rlane + j;
                    size_t idx = (size_t)row * N + col;
                    float v = acc[f][n][j];
                    if constexpr (EPI == 1) {
                        v += bias[col];
                        float g = 0.5f * v * (1.f + tanhf(0.7978845608f * (v + 0.044715f * v * v * v)));
                        outH[idx] = f2bf(g);
                    } else {
                        outH[idx] = f2bf(v);
                    }
                }
            }
        }
    }
}

// ---------------- gemm_p: 128x256 R5 skeleton, BK=64, ring-3 (combined GEMM) ------
// Dual-source K: segment 1 = (A,B) stride K1, segment 2 = (A2,B2) stride K-K1.
// EPI 4: acc+bias+add2 -> f32.
#define SLOTSZ 49152
template <int EPI>
__global__ __launch_bounds__(512, 2) void gemm_p(
    const unsigned short* __restrict__ A, const unsigned short* __restrict__ B,
    int M, int N, int K, int nby,
    float* __restrict__ outF, unsigned short* __restrict__ outH,
    const float* __restrict__ bias, const float* __restrict__ add1,
    const float* __restrict__ add2,
    const unsigned short* __restrict__ A2, const unsigned short* __restrict__ B2,
    int K1) {
    __shared__ __align__(16) char smem[3 * SLOTSZ];
    int t = threadIdx.x, lane = t & 63, w = t >> 6;
    int nwg = gridDim.x, cpx = nwg >> 3;
    int logical = (blockIdx.x & 7) * cpx + (blockIdx.x >> 3);
    int by = logical % nby, bx = logical / nby;
    int brow = by * 128, bcol = bx * 256;
    int wr = w >> 2, wc = w & 3;
    int wrb = wr * 64, wcb = wc * 64;

    int lr8 = lane >> 3;
    int lch = ((lane & 7) ^ lr8) << 3;
    const unsigned short* pa[2];
    #pragma unroll
    for (int j = 0; j < 2; ++j)
        pa[j] = A + (size_t)(brow + w * 16 + j * 8 + lr8) * K1 + lch;
    const unsigned short* pb[4];
    #pragma unroll
    for (int j = 0; j < 4; ++j) {
        int r = bcol + w * 32 + j * 8 + lr8;
        if (r > N - 1) r = N - 1;
        pb[j] = B + (size_t)r * K1 + lch;
    }
    auto stageA = [&](int slot, int j) {
        gll16(pa[j], smem + slot * SLOTSZ + (w * 16 + j * 8) * 128);
        pa[j] += 64;
    };
    auto stageB = [&](int slot, int j) {
        gll16(pb[j], smem + slot * SLOTSZ + 16384 + (w * 32 + j * 8) * 128);
        pb[j] += 64;
    };

    int arow = lane & 15;
    int swz0 = (((lane >> 4) ^ (lane & 7)) << 4);

    f32x4 acc[4][4] = {};
    const int NT = K >> 6;
    const int KS = K1 >> 6;
    #pragma unroll
    for (int j = 0; j < 2; ++j) stageA(0, j);
    #pragma unroll
    for (int j = 0; j < 4; ++j) stageB(0, j);
    #pragma unroll
    for (int j = 0; j < 2; ++j) stageA(1, j);
    #pragma unroll
    for (int j = 0; j < 4; ++j) stageB(1, j);

    int slot = 0, slot2 = 2;
    for (int kt = 0; kt < NT; ++kt) {
        if (kt + 1 < NT) { asm volatile("s_waitcnt vmcnt(6)" ::: "memory"); }
        else             { asm volatile("s_waitcnt vmcnt(0)" ::: "memory"); }
        __builtin_amdgcn_s_barrier();
        asm volatile("" ::: "memory");
        const char* Ab = smem + slot * SLOTSZ;
        const char* Bb = Ab + 16384;
        bool st = (kt + 2 < NT);
        if (B2 != nullptr && kt + 2 == KS) {
            int ld2 = K - K1;
            #pragma unroll
            for (int j = 0; j < 2; ++j)
                pa[j] = A2 + (size_t)(brow + w * 16 + j * 8 + lr8) * ld2 + lch;
            #pragma unroll
            for (int j = 0; j < 4; ++j) {
                int r = bcol + w * 32 + j * 8 + lr8;
                if (r > N - 1) r = N - 1;
                pb[j] = B2 + (size_t)r * ld2 + lch;
            }
        }
        short8 af[4], bfv[4];
        #pragma unroll
        for (int f = 0; f < 4; ++f)
            af[f] = *(const short8*)(Ab + (wrb + f * 16 + arow) * 128 + swz0);
        #pragma unroll
        for (int n = 0; n < 4; ++n)
            bfv[n] = *(const short8*)(Bb + (wcb + n * 16 + arow) * 128 + swz0);
        if (st) { stageA(slot2, 0); stageA(slot2, 1); stageB(slot2, 0); }
        __builtin_amdgcn_s_setprio(1);
        #pragma unroll
        for (int f = 0; f < 4; ++f)
            #pragma unroll
            for (int n = 0; n < 4; ++n)
                acc[f][n] = __builtin_amdgcn_mfma_f32_16x16x32_bf16(af[f], bfv[n], acc[f][n], 0, 0, 0);
        __builtin_amdgcn_s_setprio(0);
        #pragma unroll
        for (int f = 0; f < 4; ++f)
            af[f] = *(const short8*)(Ab + (wrb + f * 16 + arow) * 128 + (swz0 ^ 64));
        #pragma unroll
        for (int n = 0; n < 4; ++n)
            bfv[n] = *(const short8*)(Bb + (wcb + n * 16 + arow) * 128 + (swz0 ^ 64));
        if (st) { stageB(slot2, 1); stageB(slot2, 2); stageB(slot2, 3); }
        __builtin_amdgcn_s_setprio(1);
        #pragma unroll
        for (int f = 0; f < 4; ++f)
            #pragma unroll
            for (int n = 0; n < 4; ++n)
                acc[f][n] = __builtin_amdgcn_mfma_f32_16x16x32_bf16(af[f], bfv[n], acc[f][n], 0, 0, 0);
        __builtin_amdgcn_s_setprio(0);
        slot  = (slot  == 2) ? 0 : slot + 1;
        slot2 = (slot2 == 2) ? 0 : slot2 + 1;
    }

    int rlane = (lane >> 4) << 2, clane = lane & 15;
    #pragma unroll
    for (int f = 0; f < 4; ++f) {
        #pragma unroll
        for (int n = 0; n < 4; ++n) {
            int col = bcol + wcb + n * 16 + clane;
            if (col < N) {
                #pragma unroll
                for (int j = 0; j < 4; ++j) {
                    int row = brow + wrb + f * 16 + rlane + j;
                    size_t idx = (size_t)row * N + col;
                    float v = acc[f][n][j];
                    if constexpr (EPI == 4) {
                        outF[idx] = v + bias[col] + add2[idx];
                    } else {
                        outF[idx] = v;
                    }
                }
            }
        }
    }
}

// 64x64x64 bf16 MFMA on TSTR-padded LDS tiles.
static __device__ __forceinline__ void mm64(const unsigned short* Al, const unsigned short* Bl,
                                            f32x4* acc, int w, int lane) {
    int lr = lane & 15, kg = (lane >> 4) << 3;
    #pragma unroll
    for (int ks = 0; ks < 2; ++ks) {
        short8 a = *(const short8*)&Al[(w * 16 + lr) * TSTR + ks * 32 + kg];
        #pragma unroll
        for (int fn = 0; fn < 4; ++fn) {
            short8 bb = *(const short8*)&Bl[(fn * 16 + lr) * TSTR + ks * 32 + kg];
            acc[fn] = __builtin_amdgcn_mfma_f32_16x16x32_bf16(a, bb, acc[fn], 0, 0, 0);
        }
    }
}

// ---------------- K1: per-(b,h,chunk) intra-chunk work (dt fused) ----------------
__global__ __launch_bounds__(256) void chunk_front(const unsigned short* __restrict__ zx,
                                                   const float* __restrict__ dt_bias,
                                                   const float* __restrict__ A_log,
                                                   float* __restrict__ pcum,
                                                   unsigned short* __restrict__ ybuf,
                                                   unsigned short* __restrict__ Sbuf) {
    __shared__ __align__(16) unsigned short Cs[64*TSTR], Bsr[64*TSTR], Btr[64*TSTR],
                                            Xtr[64*TSTR], Xw[64*TSTR], Wsm[64*TSTR];
    __shared__ float dts[64], clg[64];
    int t = threadIdx.x, lane = t & 63, w = t >> 6;
    int bid = blockIdx.x;
    int c = bid & 31, h = (bid >> 5) & 63, b = bid >> 11, g = h >> 2;
    int row0 = (b << 11) + (c << 6);

    if (t < 64) {
        float raw = bf2f(zx[(size_t)(row0 + t) * DINPROJ + 10240 + h]) + dt_bias[h];
        float dt = raw > 20.f ? raw : log1pf(expf(raw));
        dts[t] = dt;
        float v = dt * (-expf(A_log[h]));
        #pragma unroll
        for (int off = 1; off < 64; off <<= 1) {
            float o = __shfl_up(v, off);
            if (lane >= off) v += o;
        }
        clg[t] = v;
        pcum[(size_t)(row0 + t) * 64 + h] = expf(v);
    }
    ushort4 xr[4];
    #pragma unroll
    for (int i = 0; i < 4; ++i) {
        int q = i * 256 + t, s = q >> 4, d4 = (q & 15) << 2;
        const unsigned short* rp = zx + (size_t)(row0 + s) * DINPROJ;
        ushort4 cv = *(const ushort4*)&rp[6144 + h * 64 + d4];
        *(ushort4*)&Cs[s * TSTR + d4] = cv;
        ushort4 bv = *(const ushort4*)&rp[5120 + g * 64 + d4];
        *(ushort4*)&Bsr[s * TSTR + d4] = bv;
        Btr[(d4 + 0) * TSTR + s] = bv.x; Btr[(d4 + 1) * TSTR + s] = bv.y;
        Btr[(d4 + 2) * TSTR + s] = bv.z; Btr[(d4 + 3) * TSTR + s] = bv.w;
        ushort4 xv = *(const ushort4*)&rp[4096 + g * 64 + d4];
        Xtr[(d4 + 0) * TSTR + s] = xv.x; Xtr[(d4 + 1) * TSTR + s] = xv.y;
        Xtr[(d4 + 2) * TSTR + s] = xv.z; Xtr[(d4 + 3) * TSTR + s] = xv.w;
        xr[i] = xv;
    }
    __syncthreads();
    float cl63 = clg[63];
    #pragma unroll
    for (int i = 0; i < 4; ++i) {
        int q = i * 256 + t, s = q >> 4, d4 = (q & 15) << 2;
        float ws = dts[s] * expf(cl63 - clg[s]);
        Xw[(d4 + 0) * TSTR + s] = f2bf(bf2f(xr[i].x) * ws);
        Xw[(d4 + 1) * TSTR + s] = f2bf(bf2f(xr[i].y) * ws);
        Xw[(d4 + 2) * TSTR + s] = f2bf(bf2f(xr[i].z) * ws);
        Xw[(d4 + 3) * TSTR + s] = f2bf(bf2f(xr[i].w) * ws);
    }
    __syncthreads();
    f32x4 accG[4] = {};
    mm64(Cs, Bsr, accG, w, lane);
    int rl = (lane >> 4) << 2, cl = lane & 15;
    #pragma unroll
    for (int fn = 0; fn < 4; ++fn) {
        #pragma unroll
        for (int j = 0; j < 4; ++j) {
            int tr = w * 16 + rl + j, rc = fn * 16 + cl;
            float val = 0.f;
            if (rc <= tr) val = accG[fn][j] * expf(clg[tr] - clg[rc]) * dts[rc];
            Wsm[tr * TSTR + rc] = f2bf(val);
        }
    }
    __syncthreads();
    f32x4 accY[4] = {};
    mm64(Wsm, Xtr, accY, w, lane);
    f32x4 accS[4] = {};
    mm64(Xw, Btr, accS, w, lane);
    size_t cb = (size_t)((((b << 6) + h) << 5) + c) * 4096;
    #pragma unroll
    for (int fn = 0; fn < 4; ++fn) {
        #pragma unroll
        for (int j = 0; j < 4; ++j) {
            int tr = w * 16 + rl + j, pc = fn * 16 + cl;
            ybuf[(size_t)(row0 + tr) * DINNER + h * 64 + pc] = f2bf(accY[fn][j]);
            Sbuf[cb + tr * 64 + pc] = f2bf(accS[fn][j]);
        }
    }
}

// ---------------- K2: inter-chunk state recurrence (in-place S -> H0) ----------------
__global__ __launch_bounds__(256) void chunk_state(unsigned short* __restrict__ SH,
                                                   const float* __restrict__ pcum) {
    int bid = blockIdx.x;
    int q = bid & 3, bh = bid >> 2;
    int b = bh >> 6, h = bh & 63;
    int t = threadIdx.x;
    float H[4];
    #pragma unroll
    for (int j = 0; j < 4; ++j) H[j] = 0.f;
    for (int c = 0; c < NC; ++c) {
        size_t base = (size_t)((((b << 6) + h) << 5) + c) * 4096 + q * 1024;
        float Tc = pcum[(size_t)((b << 11) + (c << 6) + 63) * 64 + h];
        #pragma unroll
        for (int j = 0; j < 4; ++j) {
            int e = j * 256 + t;
            unsigned short sv = SH[base + e];
            SH[base + e] = f2bf(H[j]);
            H[j] = H[j] * Tc + bf2f(sv);
        }
    }
}

// ---------------- K3: y += p_t * (C_t . H0) + Dp * x ----------------
__global__ __launch_bounds__(256) void chunk_back(const unsigned short* __restrict__ zx,
                                                  const unsigned short* __restrict__ SH,
                                                  const float* __restrict__ pcum,
                                                  const float* __restrict__ Dp,
                                                  unsigned short* __restrict__ ybuf) {
    __shared__ __align__(16) unsigned short Cs[64*TSTR], Hs[64*TSTR];
    __shared__ float ps[64];
    int t = threadIdx.x, lane = t & 63, w = t >> 6;
    int bid = blockIdx.x;
    int c = bid & 31, h = (bid >> 5) & 63, b = bid >> 11, g = h >> 2;
    int row0 = (b << 11) + (c << 6);
    size_t cb = (size_t)((((b << 6) + h) << 5) + c) * 4096;
    #pragma unroll
    for (int i = 0; i < 4; ++i) {
        int q = i * 256 + t, s = q >> 4, d4 = (q & 15) << 2;
        *(ushort4*)&Cs[s * TSTR + d4] =
            *(const ushort4*)&zx[(size_t)(row0 + s) * DINPROJ + 6144 + h * 64 + d4];
        *(ushort4*)&Hs[s * TSTR + d4] = *(const ushort4*)&SH[cb + s * 64 + d4];
    }
    if (t < 64) ps[t] = pcum[(size_t)(row0 + t) * 64 + h];
    __syncthreads();
    f32x4 acc[4] = {};
    mm64(Cs, Hs, acc, w, lane);
    float Dph = Dp[h];
    int rl = (lane >> 4) << 2, cl = lane & 15;
    #pragma unroll
    for (int fn = 0; fn < 4; ++fn) {
        #pragma unroll
        for (int j = 0; j < 4; ++j) {
            int tr = w * 16 + rl + j, pc = fn * 16 + cl;
            size_t yi = (size_t)(row0 + tr) * DINNER + h * 64 + pc;
            float xv = bf2f(zx[(size_t)(row0 + tr) * DINPROJ + 4096 + g * 64 + pc]);
            ybuf[yi] = f2bf(bf2f(ybuf[yi]) + acc[fn][j] * ps[tr] + Dph * xv);
        }
    }
}

// ---------------- gate (silu) + RMSNorm -> bf16 yf ----------------
__global__ __launch_bounds__(256) void gate_kernel(const unsigned short* __restrict__ y,
                                                   const unsigned short* __restrict__ zx,
                                                   const float* __restrict__ norm_w,
                                                   unsigned short* __restrict__ yf) {
    int row = blockIdx.x;
    int t = threadIdx.x;
    float v[16];
    float s2 = 0.f;
    #pragma unroll
    for (int i = 0; i < 16; ++i) {
        int d = i * 256 + t;
        float yv = bf2f(y[(size_t)row * DINNER + d]);
        float zv = bf2f(zx[(size_t)row * DINPROJ + d]);
        float gt = zv / (1.f + expf(-zv));
        v[i] = yv * gt;
        s2 += v[i] * v[i];
    }
    #pragma unroll
    for (int off = 1; off < 64; off <<= 1) s2 += __shfl_xor(s2, off);
    __shared__ float sb[4];
    int lane = t & 63, wv = t >> 6;
    if (lane == 0) sb[wv] = s2;
    __syncthreads();
    s2 = sb[0] + sb[1] + sb[2] + sb[3];
    float sc = rsqrtf(s2 / DINNER + EPSV);
    #pragma unroll
    for (int i = 0; i < 16; ++i) {
        int d = i * 256 + t;
        yf[(size_t)row * DINNER + d] = f2bf(v[i] * sc * norm_w[d]);
    }
}

extern "C" void kernel_launch(void* const* d_in, const int* in_sizes, int n_in,
                              void* d_out, int out_size, void* d_ws, size_t ws_size,
                              hipStream_t stream) {
    const float* hid   = (const float*)d_in[0];
    const float* ln_w  = (const float*)d_in[1];
    const float* ln_b  = (const float*)d_in[2];
    const float* w_inp = (const float*)d_in[3];
    const float* dtb   = (const float*)d_in[4];
    const float* A_log = (const float*)d_in[5];
    const float* Dp    = (const float*)d_in[6];
    const float* nw    = (const float*)d_in[7];
    const float* w_out = (const float*)d_in[8];
    const float* w_fc1 = (const float*)d_in[9];
    const float* fc1_b = (const float*)d_in[10];
    const float* w_fc2 = (const float*)d_in[11];
    const float* fc2_b = (const float*)d_in[12];

    char* ws = (char*)d_ws;
    size_t off = 0;
    auto alloc = [&](size_t bytes) { size_t o = off; off += (bytes + 255) & ~(size_t)255; return o; };
    size_t o_h    = alloc((size_t)ROWS * DMODEL * 2);
    size_t o_wi   = alloc((size_t)DINPROJ * DMODEL * 2);
    size_t o_wo   = alloc((size_t)DMODEL * DINNER * 2);
    size_t o_wf1  = alloc((size_t)INTER * DMODEL * 2);
    size_t o_wf2  = alloc((size_t)DMODEL * INTER * 2);
    size_t o_zx   = alloc((size_t)ROWS * DINPROJ * 2);
    size_t o_pc   = alloc((size_t)ROWS * NHEADS * 4);
    size_t o_y    = alloc((size_t)ROWS * DINNER * 2);
    size_t o_yf   = alloc((size_t)ROWS * DINNER * 2);
    size_t o_S    = alloc((size_t)BATCH * NHEADS * NC * HEADDIM * DSTATE * 2);

    unsigned short* h_bf  = (unsigned short*)(ws + o_h);
    unsigned short* wbi   = (unsigned short*)(ws + o_wi);
    unsigned short* wbo   = (unsigned short*)(ws + o_wo);
    unsigned short* wbf1  = (unsigned short*)(ws + o_wf1);
    unsigned short* wbf2  = (unsigned short*)(ws + o_wf2);
    unsigned short* zx    = (unsigned short*)(ws + o_zx);
    float* pcum           = (float*)(ws + o_pc);
    unsigned short* ybuf  = (unsigned short*)(ws + o_y);
    unsigned short* yf    = (unsigned short*)(ws + o_yf);
    unsigned short* Sbuf  = (unsigned short*)(ws + o_S);
    unsigned short* gelu  = (unsigned short*)(ws + o_zx);    // alias: zx dead after gate
    float* outF           = (float*)d_out;

    // 0) LayerNorm + all weight conversions in ONE dispatch
    prep_kernel<<<ROWS + 2048, 256, 0, stream>>>(
        hid, ln_w, ln_b, h_bf,
        w_inp, wbi,  (DINPROJ * DMODEL) / 4,
        w_out, wbo,  (DMODEL * DINNER) / 4,
        w_fc1, wbf1, (INTER * DMODEL) / 4,
        w_fc2, wbf2, (DMODEL * INTER) / 4);
    // 1) in_proj GEMM -> zx (bf16); 256^2 tiles: 41 col x 16 row = 656 blocks
    gemm_q<3><<<41 * 16, 512, 0, stream>>>(
        h_bf, wbi, ROWS, DINPROJ, DMODEL, 16, nullptr, zx, nullptr);
    // 2) chunked SSD scan
    chunk_front<<<BATCH * NHEADS * NC, 256, 0, stream>>>(zx, dtb, A_log, pcum, ybuf, Sbuf);
    chunk_state<<<BATCH * NHEADS * 4, 256, 0, stream>>>(Sbuf, pcum);
    chunk_back<<<BATCH * NHEADS * NC, 256, 0, stream>>>(zx, Sbuf, pcum, Dp, ybuf);
    // 3) gate + RMSNorm -> yf (bf16)
    gate_kernel<<<ROWS, 256, 0, stream>>>(ybuf, zx, nw, yf);
    // 4) fc1 GEMM + gelu -> gelu (bf16); 256^2 tiles: 32 col x 16 row = 512 blocks
    gemm_q<1><<<32 * 16, 512, 0, stream>>>(
        h_bf, wbf1, ROWS, INTER, DMODEL, 16, nullptr, gelu, fc1_b);
    // 5) combined (out_proj + fc2) GEMM over concatenated K = 4096 + 8192 (128x256)
    gemm_p<4><<<8 * 32, 512, 0, stream>>>(
        yf, wbo, ROWS, DMODEL, DINNER + INTER, 32, outF, nullptr, fc2_b, nullptr, hid,
        gelu, wbf2, DINNER);
}